// Round 1
// baseline (167.865 us; speedup 1.0000x reference)
//
#include <hip/hip_runtime.h>

// Fused: sigmoid(X@W+b) -> ec=E^T S, cc=colsum(S^2), ee=sum(E^2) in ONE pass over rows.
// Tile: 64 rows x 256 cands per block iter; 4 waves, each wave owns 64 candidate cols.
// W held in registers (96 VGPR/wave), X/E staged in LDS as bf16, S round-trips through
// LDS (transposed, wave-private) to re-shape phase-A D-frags into phase-B B-frags.

#define N_ROWS 100000
#define IN_DIM 168
#define ERR_DIM 24
#define CAND 256

#define M_TILE 64
#define NT 1563            // ceil(100000/64)
#define GRID_MAIN 512
#define XT_STRIDE 200      // 192 + 8 pad bf16 (row = 400 B, 16B-aligned, 2-way banks max)
#define ST_STRIDE 72       // 64 + 8 pad bf16 (row = 144 B, 16B-aligned, 2-way banks max)

typedef __bf16 bf16;
typedef bf16 bf16x4 __attribute__((ext_vector_type(4)));
typedef bf16 bf16x8 __attribute__((ext_vector_type(8)));
typedef float f32x4 __attribute__((ext_vector_type(4)));

// ws layout (float units): ec[32*256] | cc[256] | ee[512] ; Wpack (bf16) at byte 35840
#define EC_F 0
#define CC_F 8192
#define EE_F 8448
#define WP_BYTE 35840

__device__ __forceinline__ f32x4 mfma16(bf16x8 a, bf16x8 b, f32x4 c) {
    return __builtin_amdgcn_mfma_f32_16x16x32_bf16(a, b, c, 0, 0, 0);
}

// Pack W[168][256] f32 -> Wpack[ct(16)][kt(6)][lane(64)][8] bf16 (B-fragment order,
// zero-padded k=168..191), and zero the ec/cc accumulator region.
__global__ __launch_bounds__(256) void prep_kernel(const float* __restrict__ W,
                                                   bf16* __restrict__ wp,
                                                   float* __restrict__ zero_region) {
    int tid = blockIdx.x * 256 + threadIdx.x;   // 6144 threads total
    for (int i = tid; i < 8448; i += 6144) zero_region[i] = 0.0f;
    int ct  = tid / 384;
    int rem = tid % 384;
    int kt  = rem / 64;
    int l   = rem % 64;
    int c   = ct * 16 + (l & 15);
    int k0  = kt * 32 + (l >> 4) * 8;
    bf16x8 v;
#pragma unroll
    for (int j = 0; j < 8; ++j) {
        int k = k0 + j;
        float f = (k < IN_DIM) ? W[(size_t)k * CAND + c] : 0.0f;
        v[j] = (bf16)f;
    }
    *reinterpret_cast<bf16x8*>(wp + (size_t)tid * 8) = v;
}

__global__ __launch_bounds__(256) void fused_main(const float* __restrict__ X,
                                                  const float* __restrict__ E,
                                                  const float* __restrict__ B,
                                                  const bf16* __restrict__ wp,
                                                  float* __restrict__ ec_ws,
                                                  float* __restrict__ cc_ws,
                                                  float* __restrict__ ee_ws) {
    __shared__ bf16 XT[M_TILE * XT_STRIDE];     // [row][k]  25.6 KB
    __shared__ bf16 SigT[CAND * ST_STRIDE];     // [cand][row] 36.9 KB (wave-private col slices)
    __shared__ bf16 ET[32 * ST_STRIDE];         // [dim][row]  4.6 KB (rows 24..31 zero)
    __shared__ float red[8];

    const int tid  = threadIdx.x;
    const int wave = tid >> 6;
    const int lane = tid & 63;
    const int lo   = lane & 15;
    const int hi   = lane >> 4;
    const int wcol = wave * 64;

    // W fragments resident in registers for the whole kernel: 4 col-frags x 6 k-frags
    bf16x8 wf[4][6];
#pragma unroll
    for (int cf = 0; cf < 4; ++cf)
#pragma unroll
        for (int kt = 0; kt < 6; ++kt) {
            int ct = (wcol >> 4) + cf;
            wf[cf][kt] = *reinterpret_cast<const bf16x8*>(wp + (((size_t)(ct * 6 + kt)) * 64 + lane) * 8);
        }

    float bv[4];
#pragma unroll
    for (int cf = 0; cf < 4; ++cf) bv[cf] = B[wcol + cf * 16 + lo];

    f32x4 ec_acc[2][4];
#pragma unroll
    for (int rf = 0; rf < 2; ++rf)
#pragma unroll
        for (int cf = 0; cf < 4; ++cf) ec_acc[rf][cf] = (f32x4){0.f, 0.f, 0.f, 0.f};
    float cc_acc[4] = {0.f, 0.f, 0.f, 0.f};
    float ee_acc = 0.f;

    // zero ET rows 24..31 once (persist across tiles)
    for (int i = tid; i < 8 * ST_STRIDE; i += 256)
        ET[(24 + i / ST_STRIDE) * ST_STRIDE + (i % ST_STRIDE)] = (bf16)0.0f;

    for (int t = blockIdx.x; t < NT; t += GRID_MAIN) {
        const int row0 = t * M_TILE;
        __syncthreads();   // protect XT/ET/SigT from previous iter's readers

        // --- stage X tile: 64 rows x 42 float4 -> bf16 LDS ---
        for (int i = tid; i < 64 * 42; i += 256) {
            int r = i / 42, c4 = i % 42;
            int gr = row0 + r;
            f32x4 v = {0.f, 0.f, 0.f, 0.f};
            if (gr < N_ROWS) v = *reinterpret_cast<const f32x4*>(X + (size_t)gr * IN_DIM + c4 * 4);
            bf16x4 pk = {(bf16)v.x, (bf16)v.y, (bf16)v.z, (bf16)v.w};
            *reinterpret_cast<bf16x4*>(&XT[r * XT_STRIDE + c4 * 4]) = pk;
        }
        // zero-pad k = 168..191
        for (int i = tid; i < 64 * 6; i += 256) {
            int r = i / 6, p = i % 6;
            bf16x4 z = {(bf16)0.f, (bf16)0.f, (bf16)0.f, (bf16)0.f};
            *reinterpret_cast<bf16x4*>(&XT[r * XT_STRIDE + IN_DIM + p * 4]) = z;
        }
        // --- stage E tile transposed: ET[d][row], plus ee accumulation ---
        for (int i = tid; i < 64 * 6; i += 256) {
            int r = i / 6, p = i % 6;
            int gr = row0 + r;
            f32x4 v = {0.f, 0.f, 0.f, 0.f};
            if (gr < N_ROWS) v = *reinterpret_cast<const f32x4*>(E + (size_t)gr * ERR_DIM + p * 4);
            ee_acc += v.x * v.x + v.y * v.y + v.z * v.z + v.w * v.w;
            int d0 = p * 4;
            ET[(d0 + 0) * ST_STRIDE + r] = (bf16)v.x;
            ET[(d0 + 1) * ST_STRIDE + r] = (bf16)v.y;
            ET[(d0 + 2) * ST_STRIDE + r] = (bf16)v.z;
            ET[(d0 + 3) * ST_STRIDE + r] = (bf16)v.w;
        }
        __syncthreads();

        // --- phase A: S(64x64 per wave) = X @ W ---
        f32x4 acc[4][4];
#pragma unroll
        for (int mf = 0; mf < 4; ++mf)
#pragma unroll
            for (int cf = 0; cf < 4; ++cf) acc[mf][cf] = (f32x4){0.f, 0.f, 0.f, 0.f};
#pragma unroll
        for (int kt = 0; kt < 6; ++kt) {
            bf16x8 a[4];
#pragma unroll
            for (int mf = 0; mf < 4; ++mf)
                a[mf] = *reinterpret_cast<const bf16x8*>(&XT[(mf * 16 + lo) * XT_STRIDE + kt * 32 + hi * 8]);
#pragma unroll
            for (int mf = 0; mf < 4; ++mf)
#pragma unroll
                for (int cf = 0; cf < 4; ++cf)
                    acc[mf][cf] = mfma16(a[mf], wf[cf][kt], acc[mf][cf]);
        }

        // --- bias + sigmoid + tail mask; cc accumulate; write SigT[c][n] (wave-private) ---
#pragma unroll
        for (int mf = 0; mf < 4; ++mf) {
            const int rb = row0 + mf * 16 + hi * 4;
#pragma unroll
            for (int cf = 0; cf < 4; ++cf) {
                f32x4 v = acc[mf][cf];
                float x0 = v.x + bv[cf], x1 = v.y + bv[cf], x2 = v.z + bv[cf], x3 = v.w + bv[cf];
                float s0 = 1.0f / (1.0f + __expf(-x0));
                float s1 = 1.0f / (1.0f + __expf(-x1));
                float s2 = 1.0f / (1.0f + __expf(-x2));
                float s3 = 1.0f / (1.0f + __expf(-x3));
                if (rb + 0 >= N_ROWS) s0 = 0.0f;
                if (rb + 1 >= N_ROWS) s1 = 0.0f;
                if (rb + 2 >= N_ROWS) s2 = 0.0f;
                if (rb + 3 >= N_ROWS) s3 = 0.0f;
                cc_acc[cf] += s0 * s0 + s1 * s1 + s2 * s2 + s3 * s3;
                bf16x4 pk = {(bf16)s0, (bf16)s1, (bf16)s2, (bf16)s3};
                *reinterpret_cast<bf16x4*>(&SigT[(wcol + cf * 16 + lo) * ST_STRIDE + mf * 16 + hi * 4]) = pk;
            }
        }

        // --- phase B: ec += E^T @ S (K = 64 rows, 2 k-steps). SigT is wave-private:
        // same-wave ds_write->ds_read ordering handled by compiler lgkmcnt, no barrier. ---
#pragma unroll
        for (int kt2 = 0; kt2 < 2; ++kt2) {
            bf16x8 ea[2], sb[4];
#pragma unroll
            for (int rf = 0; rf < 2; ++rf)
                ea[rf] = *reinterpret_cast<const bf16x8*>(&ET[(rf * 16 + lo) * ST_STRIDE + kt2 * 32 + hi * 8]);
#pragma unroll
            for (int cf = 0; cf < 4; ++cf)
                sb[cf] = *reinterpret_cast<const bf16x8*>(&SigT[(wcol + cf * 16 + lo) * ST_STRIDE + kt2 * 32 + hi * 8]);
#pragma unroll
            for (int rf = 0; rf < 2; ++rf)
#pragma unroll
                for (int cf = 0; cf < 4; ++cf)
                    ec_acc[rf][cf] = mfma16(ea[rf], sb[cf], ec_acc[rf][cf]);
        }
    }

    // --- epilogue: flush partials ---
#pragma unroll
    for (int rf = 0; rf < 2; ++rf)
#pragma unroll
        for (int cf = 0; cf < 4; ++cf)
#pragma unroll
            for (int r = 0; r < 4; ++r) {
                int d = rf * 16 + hi * 4 + r;
                if (d < ERR_DIM)
                    atomicAdd(&ec_ws[d * CAND + wcol + cf * 16 + lo], ec_acc[rf][cf][r]);
            }
#pragma unroll
    for (int cf = 0; cf < 4; ++cf) {
        float v = cc_acc[cf];
        v += __shfl_down(v, 32);
        v += __shfl_down(v, 16);
        if (lane < 16) atomicAdd(&cc_ws[wcol + cf * 16 + lane], v);
    }
    // ee: wave reduce -> block reduce -> one slot per block (no atomics)
#pragma unroll
    for (int off = 32; off > 0; off >>= 1) ee_acc += __shfl_down(ee_acc, off);
    if (lane == 0) red[wave] = ee_acc;
    __syncthreads();
    if (tid == 0) ee_ws[blockIdx.x] = red[0] + red[1] + red[2] + red[3];
}

__global__ __launch_bounds__(256) void finalize(const float* __restrict__ ec_ws,
                                                const float* __restrict__ cc_ws,
                                                const float* __restrict__ ee_ws,
                                                const float* __restrict__ r,
                                                float* __restrict__ out) {
    __shared__ float tmp[4];
    __shared__ float s_ee;
    int c = threadIdx.x;   // 0..255 = candidate
    float p = ee_ws[c] + ee_ws[c + 256];
#pragma unroll
    for (int off = 32; off > 0; off >>= 1) p += __shfl_down(p, off);
    if ((c & 63) == 0) tmp[c >> 6] = p;
    __syncthreads();
    if (c == 0) s_ee = tmp[0] + tmp[1] + tmp[2] + tmp[3];
    __syncthreads();
    float ee = s_ee;
    float ccv = cc_ws[c];
    float left = 0.f;
#pragma unroll
    for (int d = 0; d < ERR_DIM; ++d) {
        float v = ec_ws[d * CAND + c];
        left += v * v;
    }
    left /= ccv;
#pragma unroll
    for (int i = 0; i < 4; ++i) out[c * 4 + i] = left - (1.0f - r[i]) * ee;
}

extern "C" void kernel_launch(void* const* d_in, const int* in_sizes, int n_in,
                              void* d_out, int out_size, void* d_ws, size_t ws_size,
                              hipStream_t stream) {
    const float* X = (const float*)d_in[0];
    const float* E = (const float*)d_in[1];
    const float* W = (const float*)d_in[2];
    const float* B = (const float*)d_in[3];
    const float* r = (const float*)d_in[4];

    float* wsf   = (float*)d_ws;
    float* ec_ws = wsf + EC_F;
    float* cc_ws = wsf + CC_F;
    float* ee_ws = wsf + EE_F;
    bf16*  wp    = (bf16*)((char*)d_ws + WP_BYTE);

    prep_kernel<<<24, 256, 0, stream>>>(W, wp, wsf);
    fused_main<<<GRID_MAIN, 256, 0, stream>>>(X, E, B, wp, ec_ws, cc_ws, ee_ws);
    finalize<<<1, 256, 0, stream>>>(ec_ws, cc_ws, ee_ws, r, (float*)d_out);
}

// Round 3
// 166.392 us; speedup vs baseline: 1.0089x; 1.0089x over previous
//
#include <hip/hip_runtime.h>

// Fused: sigmoid(X@W+b) -> ec=E^T S, cc=colsum(S^2), ee=sum(E^2) in ONE pass over rows.
// Tile: 64 rows x 256 cands per block iter; 4 waves, each wave owns 64 candidate cols.
// W held in registers, X/E staged in LDS as bf16 with BATCH-ISSUED loads (all 13
// vec4 loads in flight before first consume -> one HBM latency per tile, not 11).
// Sigmoid via v_rcp+v_exp (bf16-bound output, full div was ~10 ops). ec/cc flushed
// to 8 spread copies to cut atomic same-line serialization; reduced in finalize.
// __launch_bounds__(256,2): LDS (67.5KB) caps at 2 blocks/CU anyway -> give the
// allocator the full 256-VGPR budget so the batched staging regs never spill.

#define N_ROWS 100000
#define IN_DIM 168
#define ERR_DIM 24
#define CAND 256

#define M_TILE 64
#define NT 1563            // ceil(100000/64)
#define GRID_MAIN 512
#define XT_STRIDE 200      // 192 + 8 pad bf16
#define ST_STRIDE 72       // 64 + 8 pad bf16
#define NCOPY 8

typedef __bf16 bf16;
typedef bf16 bf16x4 __attribute__((ext_vector_type(4)));
typedef bf16 bf16x8 __attribute__((ext_vector_type(8)));
typedef float f32x4 __attribute__((ext_vector_type(4)));

// ws float layout: ec8[8*6144] | cc8[8*256] | ee[512] ; wpack bf16 after
#define EC_F 0
#define CC_F 49152
#define EE_F 51200
#define ZERO_N 51712
#define WP_F 51712

__device__ __forceinline__ f32x4 mfma16(bf16x8 a, bf16x8 b, f32x4 c) {
    return __builtin_amdgcn_mfma_f32_16x16x32_bf16(a, b, c, 0, 0, 0);
}

__device__ __forceinline__ float fast_sigmoid(float x) {
    // rcp is ~1ulp; result is rounded to bf16 (8-bit mantissa) anyway.
    return __builtin_amdgcn_rcpf(1.0f + __expf(-x));
}

// Pack W[168][256] f32 -> Wpack[ct(16)][kt(6)][lane(64)][8] bf16 (B-fragment order,
// zero-padded k=168..191), and zero the ec/cc/ee accumulator region.
__global__ __launch_bounds__(256) void prep_kernel(const float* __restrict__ W,
                                                   bf16* __restrict__ wp,
                                                   float* __restrict__ zero_region) {
    int tid = blockIdx.x * 256 + threadIdx.x;   // 6144 threads total
    for (int i = tid; i < ZERO_N; i += 6144) zero_region[i] = 0.0f;
    int ct  = tid / 384;
    int rem = tid % 384;
    int kt  = rem / 64;
    int l   = rem % 64;
    int c   = ct * 16 + (l & 15);
    int k0  = kt * 32 + (l >> 4) * 8;
    bf16x8 v;
#pragma unroll
    for (int j = 0; j < 8; ++j) {
        int k = k0 + j;
        float f = (k < IN_DIM) ? W[(size_t)k * CAND + c] : 0.0f;
        v[j] = (bf16)f;
    }
    *reinterpret_cast<bf16x8*>(wp + (size_t)tid * 8) = v;
}

__global__ __launch_bounds__(256, 2) void fused_main(const float* __restrict__ X,
                                                     const float* __restrict__ E,
                                                     const float* __restrict__ B,
                                                     const bf16* __restrict__ wp,
                                                     float* __restrict__ ec_ws,
                                                     float* __restrict__ cc_ws,
                                                     float* __restrict__ ee_ws) {
    __shared__ bf16 XT[M_TILE * XT_STRIDE];     // [row][k]  25.6 KB
    __shared__ bf16 SigT[CAND * ST_STRIDE];     // [cand][row] 36.9 KB (wave-private col slices)
    __shared__ bf16 ET[32 * ST_STRIDE];         // [dim][row]  4.6 KB (rows 24..31 zero)
    __shared__ float red[8];

    const int tid  = threadIdx.x;
    const int wave = tid >> 6;
    const int lane = tid & 63;
    const int lo   = lane & 15;
    const int hi   = lane >> 4;
    const int wcol = wave * 64;

    // W fragments resident in registers for the whole kernel: 4 col-frags x 6 k-frags
    bf16x8 wf[4][6];
#pragma unroll
    for (int cf = 0; cf < 4; ++cf)
#pragma unroll
        for (int kt = 0; kt < 6; ++kt) {
            int ct = (wcol >> 4) + cf;
            wf[cf][kt] = *reinterpret_cast<const bf16x8*>(wp + (((size_t)(ct * 6 + kt)) * 64 + lane) * 8);
        }

    float bv[4];
#pragma unroll
    for (int cf = 0; cf < 4; ++cf) bv[cf] = B[wcol + cf * 16 + lo];

    f32x4 ec_acc[2][4];
#pragma unroll
    for (int rf = 0; rf < 2; ++rf)
#pragma unroll
        for (int cf = 0; cf < 4; ++cf) ec_acc[rf][cf] = (f32x4){0.f, 0.f, 0.f, 0.f};
    float cc_acc[4] = {0.f, 0.f, 0.f, 0.f};
    float ee_acc = 0.f;

    // one-time zeroing (persist across tiles): ET rows 24..31, XT pad cols 168..191
    for (int i = tid; i < 8 * ST_STRIDE; i += 256)
        ET[(24 + i / ST_STRIDE) * ST_STRIDE + (i % ST_STRIDE)] = (bf16)0.0f;
    {
        bf16x4 z = {(bf16)0.f, (bf16)0.f, (bf16)0.f, (bf16)0.f};
        for (int i = tid; i < 64 * 6; i += 256) {
            int r = i / 6, p = i % 6;
            *reinterpret_cast<bf16x4*>(&XT[r * XT_STRIDE + IN_DIM + p * 4]) = z;
        }
    }

    for (int t = blockIdx.x; t < NT; t += GRID_MAIN) {
        const int row0 = t * M_TILE;
        __syncthreads();   // previous iter's LDS readers done

        // ---- BATCH-ISSUE all staging loads (no consumes in between) ----
        f32x4 xr[11], er[2];
#pragma unroll
        for (int j = 0; j < 11; ++j) {
            int idx = tid + j * 256;
            int r = idx / 42, c4 = idx - r * 42;
            int gr = row0 + r;
            f32x4 v = {0.f, 0.f, 0.f, 0.f};
            if (idx < 2688 && gr < N_ROWS)
                v = *reinterpret_cast<const f32x4*>(X + (size_t)gr * IN_DIM + c4 * 4);
            xr[j] = v;
        }
#pragma unroll
        for (int j = 0; j < 2; ++j) {
            int idx = tid + j * 256;
            int r = idx / 6, p = idx - r * 6;
            int gr = row0 + r;
            f32x4 v = {0.f, 0.f, 0.f, 0.f};
            if (idx < 384 && gr < N_ROWS)
                v = *reinterpret_cast<const f32x4*>(E + (size_t)gr * ERR_DIM + p * 4);
            er[j] = v;
        }

        // ---- consume in issue order: convert + LDS write ----
#pragma unroll
        for (int j = 0; j < 11; ++j) {
            int idx = tid + j * 256;
            if (idx < 2688) {
                int r = idx / 42, c4 = idx - r * 42;
                f32x4 v = xr[j];
                bf16x4 pk = {(bf16)v.x, (bf16)v.y, (bf16)v.z, (bf16)v.w};
                *reinterpret_cast<bf16x4*>(&XT[r * XT_STRIDE + c4 * 4]) = pk;
            }
        }
#pragma unroll
        for (int j = 0; j < 2; ++j) {
            int idx = tid + j * 256;
            if (idx < 384) {
                int r = idx / 6, p = idx - r * 6;
                f32x4 v = er[j];
                ee_acc += v.x * v.x + v.y * v.y + v.z * v.z + v.w * v.w;
                int d0 = p * 4;
                ET[(d0 + 0) * ST_STRIDE + r] = (bf16)v.x;
                ET[(d0 + 1) * ST_STRIDE + r] = (bf16)v.y;
                ET[(d0 + 2) * ST_STRIDE + r] = (bf16)v.z;
                ET[(d0 + 3) * ST_STRIDE + r] = (bf16)v.w;
            }
        }
        __syncthreads();

        // --- phase A: S(64x64 per wave) = X @ W ---
        f32x4 acc[4][4];
#pragma unroll
        for (int mf = 0; mf < 4; ++mf)
#pragma unroll
            for (int cf = 0; cf < 4; ++cf) acc[mf][cf] = (f32x4){0.f, 0.f, 0.f, 0.f};
#pragma unroll
        for (int kt = 0; kt < 6; ++kt) {
            bf16x8 a[4];
#pragma unroll
            for (int mf = 0; mf < 4; ++mf)
                a[mf] = *reinterpret_cast<const bf16x8*>(&XT[(mf * 16 + lo) * XT_STRIDE + kt * 32 + hi * 8]);
#pragma unroll
            for (int mf = 0; mf < 4; ++mf)
#pragma unroll
                for (int cf = 0; cf < 4; ++cf)
                    acc[mf][cf] = mfma16(a[mf], wf[cf][kt], acc[mf][cf]);
        }

        // --- bias + fast sigmoid + tail mask; cc accumulate; write SigT (wave-private) ---
#pragma unroll
        for (int mf = 0; mf < 4; ++mf) {
            const int rb = row0 + mf * 16 + hi * 4;
#pragma unroll
            for (int cf = 0; cf < 4; ++cf) {
                f32x4 v = acc[mf][cf];
                float s0 = fast_sigmoid(v.x + bv[cf]);
                float s1 = fast_sigmoid(v.y + bv[cf]);
                float s2 = fast_sigmoid(v.z + bv[cf]);
                float s3 = fast_sigmoid(v.w + bv[cf]);
                if (rb + 0 >= N_ROWS) s0 = 0.0f;
                if (rb + 1 >= N_ROWS) s1 = 0.0f;
                if (rb + 2 >= N_ROWS) s2 = 0.0f;
                if (rb + 3 >= N_ROWS) s3 = 0.0f;
                cc_acc[cf] += s0 * s0 + s1 * s1 + s2 * s2 + s3 * s3;
                bf16x4 pk = {(bf16)s0, (bf16)s1, (bf16)s2, (bf16)s3};
                *reinterpret_cast<bf16x4*>(&SigT[(wcol + cf * 16 + lo) * ST_STRIDE + mf * 16 + hi * 4]) = pk;
            }
        }

        // --- phase B: ec += E^T @ S (wave-private SigT; same-wave lgkmcnt ordering) ---
#pragma unroll
        for (int kt2 = 0; kt2 < 2; ++kt2) {
            bf16x8 ea[2], sb[4];
#pragma unroll
            for (int rf = 0; rf < 2; ++rf)
                ea[rf] = *reinterpret_cast<const bf16x8*>(&ET[(rf * 16 + lo) * ST_STRIDE + kt2 * 32 + hi * 8]);
#pragma unroll
            for (int cf = 0; cf < 4; ++cf)
                sb[cf] = *reinterpret_cast<const bf16x8*>(&SigT[(wcol + cf * 16 + lo) * ST_STRIDE + kt2 * 32 + hi * 8]);
#pragma unroll
            for (int rf = 0; rf < 2; ++rf)
#pragma unroll
                for (int cf = 0; cf < 4; ++cf)
                    ec_acc[rf][cf] = mfma16(ea[rf], sb[cf], ec_acc[rf][cf]);
        }
    }

    // --- epilogue: flush partials into 8 spread copies ---
    const int copy = blockIdx.x & (NCOPY - 1);
#pragma unroll
    for (int rf = 0; rf < 2; ++rf)
#pragma unroll
        for (int cf = 0; cf < 4; ++cf)
#pragma unroll
            for (int rr = 0; rr < 4; ++rr) {
                int d = rf * 16 + hi * 4 + rr;
                if (d < ERR_DIM)
                    atomicAdd(&ec_ws[copy * (ERR_DIM * CAND) + d * CAND + wcol + cf * 16 + lo],
                              ec_acc[rf][cf][rr]);
            }
#pragma unroll
    for (int cf = 0; cf < 4; ++cf) {
        float v = cc_acc[cf];
        v += __shfl_down(v, 32);
        v += __shfl_down(v, 16);
        if (lane < 16) atomicAdd(&cc_ws[copy * CAND + wcol + cf * 16 + lane], v);
    }
#pragma unroll
    for (int off = 32; off > 0; off >>= 1) ee_acc += __shfl_down(ee_acc, off);
    if (lane == 0) red[wave] = ee_acc;
    __syncthreads();
    if (tid == 0) ee_ws[blockIdx.x] = red[0] + red[1] + red[2] + red[3];
}

__global__ __launch_bounds__(256) void finalize(const float* __restrict__ ec_ws,
                                                const float* __restrict__ cc_ws,
                                                const float* __restrict__ ee_ws,
                                                const float* __restrict__ r,
                                                float* __restrict__ out) {
    __shared__ float tmp[4];
    __shared__ float s_ee;
    int c = threadIdx.x;   // 0..255 = candidate
    float p = ee_ws[c] + ee_ws[c + 256];
#pragma unroll
    for (int off = 32; off > 0; off >>= 1) p += __shfl_down(p, off);
    if ((c & 63) == 0) tmp[c >> 6] = p;
    __syncthreads();
    if (c == 0) s_ee = tmp[0] + tmp[1] + tmp[2] + tmp[3];
    __syncthreads();
    float ee = s_ee;
    float ccv = 0.f;
#pragma unroll
    for (int cp = 0; cp < NCOPY; ++cp) ccv += cc_ws[cp * CAND + c];
    float left = 0.f;
#pragma unroll
    for (int d = 0; d < ERR_DIM; ++d) {
        float v = 0.f;
#pragma unroll
        for (int cp = 0; cp < NCOPY; ++cp) v += ec_ws[cp * (ERR_DIM * CAND) + d * CAND + c];
        left += v * v;
    }
    left /= ccv;
#pragma unroll
    for (int i = 0; i < 4; ++i) out[c * 4 + i] = left - (1.0f - r[i]) * ee;
}

extern "C" void kernel_launch(void* const* d_in, const int* in_sizes, int n_in,
                              void* d_out, int out_size, void* d_ws, size_t ws_size,
                              hipStream_t stream) {
    const float* X = (const float*)d_in[0];
    const float* E = (const float*)d_in[1];
    const float* W = (const float*)d_in[2];
    const float* B = (const float*)d_in[3];
    const float* r = (const float*)d_in[4];

    float* wsf   = (float*)d_ws;
    float* ec_ws = wsf + EC_F;
    float* cc_ws = wsf + CC_F;
    float* ee_ws = wsf + EE_F;
    bf16*  wp    = (bf16*)(wsf + WP_F);

    prep_kernel<<<24, 256, 0, stream>>>(W, wp, wsf);
    fused_main<<<GRID_MAIN, 256, 0, stream>>>(X, E, B, wp, ec_ws, cc_ws, ee_ws);
    finalize<<<1, 256, 0, stream>>>(ec_ws, cc_ws, ee_ws, r, (float*)d_out);
}

// Round 5
// 160.445 us; speedup vs baseline: 1.0462x; 1.0371x over previous
//
#include <hip/hip_runtime.h>

// Fused: sigmoid(X@W+b) -> ec=E^T S, cc=colsum(S^2), ee=sum(E^2), one pass over rows.
// ROUND-4 RETILE: 256 cands split over 4 BLOCKS (cand-group cg), not 4 waves.
// Per wave: 16 cands -> wf 24 VGPR (was 96), acc 16 (was 64), ec_acc 8 (was 32);
// peak ~110 regs incl. 11-load staging batch -> fits 128, NO SPILLS (r3: VGPR=128
// forced spills, 36MB scratch writes). LDS 39.5KB -> 4 blocks/CU, 16 waves/CU.
// X re-read by 4 sibling blocks is served by L2: blockIdx swizzled so siblings
// (same row-tile, cg 0..3) land on the SAME XCD (pid === rblk mod 8).

#define N_ROWS 100000
#define IN_DIM 168
#define ERR_DIM 24
#define CAND 256

#define M_TILE 64
#define NT 1563            // ceil(100000/64)
#define RBLKS 256          // row-block slots; grid = 4*RBLKS = 1024 (all co-resident)
#define XT_STRIDE 200      // 192 + 8 pad bf16 (row 400 B; A-frag b128 slots uniform)
#define ST_STRIDE 72       // 64 + 8 pad bf16 (144 B rows; b128 slots uniform)
#define NCOPY 8

typedef __bf16 bf16;
typedef bf16 bf16x4 __attribute__((ext_vector_type(4)));
typedef bf16 bf16x8 __attribute__((ext_vector_type(8)));
typedef float f32x4 __attribute__((ext_vector_type(4)));

// ws float layout: ec8[8][24][256] | cc8[8][256] | ee[256] ; wpack bf16 after
#define EC_F 0
#define CC_F 49152
#define EE_F 51200
#define ZERO_N 51456
#define WP_F 51712

__device__ __forceinline__ f32x4 mfma16(bf16x8 a, bf16x8 b, f32x4 c) {
    return __builtin_amdgcn_mfma_f32_16x16x32_bf16(a, b, c, 0, 0, 0);
}

__device__ __forceinline__ float fast_sigmoid(float x) {
    return __builtin_amdgcn_rcpf(1.0f + __expf(-x));
}

// Pack W[168][256] f32 -> Wpack[ct(16)][kt(6)][lane(64)][8] bf16 (B-fragment order,
// zero-padded k=168..191), and zero the ec/cc/ee accumulator region.
__global__ __launch_bounds__(256) void prep_kernel(const float* __restrict__ W,
                                                   bf16* __restrict__ wp,
                                                   float* __restrict__ zero_region) {
    int tid = blockIdx.x * 256 + threadIdx.x;   // 6144 threads total
    for (int i = tid; i < ZERO_N; i += 6144) zero_region[i] = 0.0f;
    int ct  = tid / 384;
    int rem = tid % 384;
    int kt  = rem / 64;
    int l   = rem % 64;
    int c   = ct * 16 + (l & 15);
    int k0  = kt * 32 + (l >> 4) * 8;
    bf16x8 v;
#pragma unroll
    for (int j = 0; j < 8; ++j) {
        int k = k0 + j;
        float f = (k < IN_DIM) ? W[(size_t)k * CAND + c] : 0.0f;
        v[j] = (bf16)f;
    }
    *reinterpret_cast<bf16x8*>(wp + (size_t)tid * 8) = v;
}

__global__ __launch_bounds__(256, 4) void fused_main(const float* __restrict__ X,
                                                     const float* __restrict__ E,
                                                     const float* __restrict__ B,
                                                     const bf16* __restrict__ wp,
                                                     float* __restrict__ ec_ws,
                                                     float* __restrict__ cc_ws,
                                                     float* __restrict__ ee_ws) {
    __shared__ bf16 XT[M_TILE * XT_STRIDE];     // [row][k]   25.6 KB
    __shared__ bf16 SigT[64 * ST_STRIDE];       // [cand][row] 9.2 KB (wave-private 16-rows)
    __shared__ bf16 ET[32 * ST_STRIDE];         // [dim][row]  4.6 KB (rows 24..31 zero)
    __shared__ float red[8];

    // swizzle: pid = (rblk%8) + 8*((rblk/8) + 32*cg)  -> siblings share an XCD
    const int pid  = blockIdx.x;
    const int cg   = (pid >> 3) >> 5;                       // candidate group 0..3
    const int rblk = (((pid >> 3) & 31) << 3) | (pid & 7);  // row-block 0..255

    const int tid  = threadIdx.x;
    const int wave = tid >> 6;
    const int lane = tid & 63;
    const int lo   = lane & 15;
    const int hi   = lane >> 4;
    const int ct   = cg * 4 + wave;          // global 16-cand tile owned by this wave
    const int cand = ct * 16 + lo;           // this lane's candidate column

    // W fragments resident in registers: 6 k-frags (24 VGPR)
    bf16x8 wf[6];
#pragma unroll
    for (int kt = 0; kt < 6; ++kt)
        wf[kt] = *reinterpret_cast<const bf16x8*>(wp + (((size_t)(ct * 6 + kt)) * 64 + lane) * 8);
    const float bv = B[cand];

    f32x4 ec_acc[2];
    ec_acc[0] = (f32x4){0.f, 0.f, 0.f, 0.f};
    ec_acc[1] = (f32x4){0.f, 0.f, 0.f, 0.f};
    float cc_acc = 0.f;
    float ee_acc = 0.f;

    // one-time zeroing: ET rows 24..31, XT pad cols 168..191
    for (int i = tid; i < 8 * ST_STRIDE; i += 256)
        ET[(24 + i / ST_STRIDE) * ST_STRIDE + (i % ST_STRIDE)] = (bf16)0.0f;
    {
        bf16x4 z = {(bf16)0.f, (bf16)0.f, (bf16)0.f, (bf16)0.f};
        for (int i = tid; i < 64 * 6; i += 256) {
            int r = i / 6, p = i % 6;
            *reinterpret_cast<bf16x4*>(&XT[r * XT_STRIDE + IN_DIM + p * 4]) = z;
        }
    }

    for (int t = rblk; t < NT; t += RBLKS) {
        const int row0 = t * M_TILE;
        __syncthreads();   // previous iter's LDS readers done

        // ---- BATCH-ISSUE staging loads (fits regs now: base usage is small) ----
        f32x4 xr[11], er[2];
#pragma unroll
        for (int j = 0; j < 11; ++j) {
            int idx = tid + j * 256;
            int r = idx / 42, c4 = idx - r * 42;
            int gr = row0 + r;
            f32x4 v = {0.f, 0.f, 0.f, 0.f};
            if (idx < 2688 && gr < N_ROWS)
                v = *reinterpret_cast<const f32x4*>(X + (size_t)gr * IN_DIM + c4 * 4);
            xr[j] = v;
        }
#pragma unroll
        for (int j = 0; j < 2; ++j) {
            int idx = tid + j * 256;
            int r = idx / 6, p = idx - r * 6;
            int gr = row0 + r;
            f32x4 v = {0.f, 0.f, 0.f, 0.f};
            if (idx < 384 && gr < N_ROWS)
                v = *reinterpret_cast<const f32x4*>(E + (size_t)gr * ERR_DIM + p * 4);
            er[j] = v;
        }

        // ---- consume in issue order: convert + LDS write ----
#pragma unroll
        for (int j = 0; j < 11; ++j) {
            int idx = tid + j * 256;
            if (idx < 2688) {
                int r = idx / 42, c4 = idx - r * 42;
                f32x4 v = xr[j];
                bf16x4 pk = {(bf16)v.x, (bf16)v.y, (bf16)v.z, (bf16)v.w};
                *reinterpret_cast<bf16x4*>(&XT[r * XT_STRIDE + c4 * 4]) = pk;
            }
        }
#pragma unroll
        for (int j = 0; j < 2; ++j) {
            int idx = tid + j * 256;
            if (idx < 384) {
                int r = idx / 6, p = idx - r * 6;
                f32x4 v = er[j];
                if (cg == 0)   // ee counted once, not 4x
                    ee_acc += v.x * v.x + v.y * v.y + v.z * v.z + v.w * v.w;
                int d0 = p * 4;
                ET[(d0 + 0) * ST_STRIDE + r] = (bf16)v.x;
                ET[(d0 + 1) * ST_STRIDE + r] = (bf16)v.y;
                ET[(d0 + 2) * ST_STRIDE + r] = (bf16)v.z;
                ET[(d0 + 3) * ST_STRIDE + r] = (bf16)v.w;
            }
        }
        __syncthreads();

        // --- phase A: S(64 rows x 16 cands per wave) = X @ W ---
        f32x4 acc[4];
#pragma unroll
        for (int mf = 0; mf < 4; ++mf) acc[mf] = (f32x4){0.f, 0.f, 0.f, 0.f};
#pragma unroll
        for (int kt = 0; kt < 6; ++kt) {
            bf16x8 a[4];
#pragma unroll
            for (int mf = 0; mf < 4; ++mf)
                a[mf] = *reinterpret_cast<const bf16x8*>(&XT[(mf * 16 + lo) * XT_STRIDE + kt * 32 + hi * 8]);
#pragma unroll
            for (int mf = 0; mf < 4; ++mf)
                acc[mf] = mfma16(a[mf], wf[kt], acc[mf]);
        }

        // --- bias + fast sigmoid + tail mask; cc accumulate; write SigT (wave-private) ---
#pragma unroll
        for (int mf = 0; mf < 4; ++mf) {
            const int rb = row0 + mf * 16 + hi * 4;
            f32x4 v = acc[mf];
            float s0 = fast_sigmoid(v.x + bv);
            float s1 = fast_sigmoid(v.y + bv);
            float s2 = fast_sigmoid(v.z + bv);
            float s3 = fast_sigmoid(v.w + bv);
            if (rb + 0 >= N_ROWS) s0 = 0.0f;
            if (rb + 1 >= N_ROWS) s1 = 0.0f;
            if (rb + 2 >= N_ROWS) s2 = 0.0f;
            if (rb + 3 >= N_ROWS) s3 = 0.0f;
            cc_acc += s0 * s0 + s1 * s1 + s2 * s2 + s3 * s3;
            bf16x4 pk = {(bf16)s0, (bf16)s1, (bf16)s2, (bf16)s3};
            *reinterpret_cast<bf16x4*>(&SigT[(wave * 16 + lo) * ST_STRIDE + mf * 16 + hi * 4]) = pk;
        }

        // --- phase B: ec += E^T @ S (wave-private SigT; same-wave lgkmcnt ordering) ---
#pragma unroll
        for (int kt2 = 0; kt2 < 2; ++kt2) {
            bf16x8 ea0 = *reinterpret_cast<const bf16x8*>(&ET[(0 * 16 + lo) * ST_STRIDE + kt2 * 32 + hi * 8]);
            bf16x8 ea1 = *reinterpret_cast<const bf16x8*>(&ET[(1 * 16 + lo) * ST_STRIDE + kt2 * 32 + hi * 8]);
            bf16x8 sb  = *reinterpret_cast<const bf16x8*>(&SigT[(wave * 16 + lo) * ST_STRIDE + kt2 * 32 + hi * 8]);
            ec_acc[0] = mfma16(ea0, sb, ec_acc[0]);
            ec_acc[1] = mfma16(ea1, sb, ec_acc[1]);
        }
    }

    // --- epilogue: flush partials into 8 spread copies ---
    const int copy = rblk & (NCOPY - 1);
#pragma unroll
    for (int rf = 0; rf < 2; ++rf)
#pragma unroll
        for (int rr = 0; rr < 4; ++rr) {
            int d = rf * 16 + hi * 4 + rr;
            if (d < ERR_DIM)
                atomicAdd(&ec_ws[copy * (ERR_DIM * CAND) + d * CAND + cand], ec_acc[rf][rr]);
        }
    {
        float v = cc_acc;
        v += __shfl_down(v, 32);
        v += __shfl_down(v, 16);
        if (lane < 16) atomicAdd(&cc_ws[copy * CAND + ct * 16 + lane], v);
    }
    if (cg == 0) {
#pragma unroll
        for (int off = 32; off > 0; off >>= 1) ee_acc += __shfl_down(ee_acc, off);
        if (lane == 0) red[wave] = ee_acc;
    }
    __syncthreads();
    if (cg == 0 && tid == 0) ee_ws[rblk] = red[0] + red[1] + red[2] + red[3];
}

__global__ __launch_bounds__(256) void finalize(const float* __restrict__ ec_ws,
                                                const float* __restrict__ cc_ws,
                                                const float* __restrict__ ee_ws,
                                                const float* __restrict__ r,
                                                float* __restrict__ out) {
    __shared__ float tmp[4];
    __shared__ float s_ee;
    int c = threadIdx.x;   // 0..255 = candidate
    float p = ee_ws[c];
#pragma unroll
    for (int off = 32; off > 0; off >>= 1) p += __shfl_down(p, off);
    if ((c & 63) == 0) tmp[c >> 6] = p;
    __syncthreads();
    if (c == 0) s_ee = tmp[0] + tmp[1] + tmp[2] + tmp[3];
    __syncthreads();
    float ee = s_ee;
    float ccv = 0.f;
#pragma unroll
    for (int cp = 0; cp < NCOPY; ++cp) ccv += cc_ws[cp * CAND + c];
    float left = 0.f;
#pragma unroll
    for (int d = 0; d < ERR_DIM; ++d) {
        float v = 0.f;
#pragma unroll
        for (int cp = 0; cp < NCOPY; ++cp) v += ec_ws[cp * (ERR_DIM * CAND) + d * CAND + c];
        left += v * v;
    }
    left /= ccv;
#pragma unroll
    for (int i = 0; i < 4; ++i) out[c * 4 + i] = left - (1.0f - r[i]) * ee;
}

extern "C" void kernel_launch(void* const* d_in, const int* in_sizes, int n_in,
                              void* d_out, int out_size, void* d_ws, size_t ws_size,
                              hipStream_t stream) {
    const float* X = (const float*)d_in[0];
    const float* E = (const float*)d_in[1];
    const float* W = (const float*)d_in[2];
    const float* B = (const float*)d_in[3];
    const float* r = (const float*)d_in[4];

    float* wsf   = (float*)d_ws;
    float* ec_ws = wsf + EC_F;
    float* cc_ws = wsf + CC_F;
    float* ee_ws = wsf + EE_F;
    bf16*  wp    = (bf16*)(wsf + WP_F);

    prep_kernel<<<24, 256, 0, stream>>>(W, wp, wsf);
    fused_main<<<4 * RBLKS, 256, 0, stream>>>(X, E, B, wp, ec_ws, cc_ws, ee_ws);
    finalize<<<1, 256, 0, stream>>>(ec_ws, cc_ws, ee_ws, r, (float*)d_out);
}

// Round 7
// 135.599 us; speedup vs baseline: 1.2379x; 1.1832x over previous
//
#include <hip/hip_runtime.h>

// Fused: sigmoid(X@W+b) -> ec=E^T S, cc=colsum(S^2), ee=sum(E^2), one pass over rows.
// Tiling (r4): 256 cands over 4 blocks (cg), 16 cands/wave; wf 24 VGPR, acc 16,
// ec_acc 8; X/E staged to LDS bf16 with an 11+2 batch-issued load block.
// ROUND-6 FIX: single-arg __launch_bounds__. Evidence r3/r5: with (256,k) the
// allocator grants only 256/k arch VGPRs (unified VGPR/AGPR file splits when MFMA
// accs live in AGPRs) -> k=4 gave 64 VGPRs -> ~20MB scratch spill traffic on the
// staging critical path. r1 precedent: single-arg -> compiler picked 160, zero
// spill. Working set here ~120 -> expect ~128-160, no spill, 3-4 blocks/CU.

#define N_ROWS 100000
#define IN_DIM 168
#define ERR_DIM 24
#define CAND 256

#define M_TILE 64
#define NT 1563            // ceil(100000/64)
#define RBLKS 256          // row-block slots; grid = 4*RBLKS = 1024
#define XT_STRIDE 200      // 192 + 8 pad bf16
#define ST_STRIDE 72       // 64 + 8 pad bf16
#define NCOPY 8

typedef __bf16 bf16;
typedef bf16 bf16x4 __attribute__((ext_vector_type(4)));
typedef bf16 bf16x8 __attribute__((ext_vector_type(8)));
typedef float f32x4 __attribute__((ext_vector_type(4)));

// ws float layout: ec8[8][24][256] | cc8[8][256] | ee[256] ; wpack bf16 after
#define EC_F 0
#define CC_F 49152
#define EE_F 51200
#define ZERO_N 51456
#define WP_F 51712

__device__ __forceinline__ f32x4 mfma16(bf16x8 a, bf16x8 b, f32x4 c) {
    return __builtin_amdgcn_mfma_f32_16x16x32_bf16(a, b, c, 0, 0, 0);
}

__device__ __forceinline__ float fast_sigmoid(float x) {
    return __builtin_amdgcn_rcpf(1.0f + __expf(-x));
}

// Pack W[168][256] f32 -> Wpack[ct(16)][kt(6)][lane(64)][8] bf16 (B-fragment order,
// zero-padded k=168..191), and zero the ec/cc/ee accumulator region.
__global__ __launch_bounds__(256) void prep_kernel(const float* __restrict__ W,
                                                   bf16* __restrict__ wp,
                                                   float* __restrict__ zero_region) {
    int tid = blockIdx.x * 256 + threadIdx.x;   // 6144 threads total
    for (int i = tid; i < ZERO_N; i += 6144) zero_region[i] = 0.0f;
    int ct  = tid / 384;
    int rem = tid % 384;
    int kt  = rem / 64;
    int l   = rem % 64;
    int c   = ct * 16 + (l & 15);
    int k0  = kt * 32 + (l >> 4) * 8;
    bf16x8 v;
#pragma unroll
    for (int j = 0; j < 8; ++j) {
        int k = k0 + j;
        float f = (k < IN_DIM) ? W[(size_t)k * CAND + c] : 0.0f;
        v[j] = (bf16)f;
    }
    *reinterpret_cast<bf16x8*>(wp + (size_t)tid * 8) = v;
}

__global__ __launch_bounds__(256) void fused_main(const float* __restrict__ X,
                                                  const float* __restrict__ E,
                                                  const float* __restrict__ B,
                                                  const bf16* __restrict__ wp,
                                                  float* __restrict__ ec_ws,
                                                  float* __restrict__ cc_ws,
                                                  float* __restrict__ ee_ws) {
    __shared__ bf16 XT[M_TILE * XT_STRIDE];     // [row][k]   25.6 KB
    __shared__ bf16 SigT[64 * ST_STRIDE];       // [cand][row] 9.2 KB (wave-private 16-rows)
    __shared__ bf16 ET[32 * ST_STRIDE];         // [dim][row]  4.6 KB (rows 24..31 zero)
    __shared__ float red[8];

    // swizzle: pid = (rblk%8) + 8*((rblk/8) + 32*cg)  -> siblings share an XCD
    const int pid  = blockIdx.x;
    const int cg   = (pid >> 3) >> 5;                       // candidate group 0..3
    const int rblk = (((pid >> 3) & 31) << 3) | (pid & 7);  // row-block 0..255

    const int tid  = threadIdx.x;
    const int wave = tid >> 6;
    const int lane = tid & 63;
    const int lo   = lane & 15;
    const int hi   = lane >> 4;
    const int ct   = cg * 4 + wave;          // global 16-cand tile owned by this wave
    const int cand = ct * 16 + lo;           // this lane's candidate column

    // W fragments resident in registers: 6 k-frags (24 VGPR)
    bf16x8 wf[6];
#pragma unroll
    for (int kt = 0; kt < 6; ++kt)
        wf[kt] = *reinterpret_cast<const bf16x8*>(wp + (((size_t)(ct * 6 + kt)) * 64 + lane) * 8);
    const float bv = B[cand];

    f32x4 ec_acc[2];
    ec_acc[0] = (f32x4){0.f, 0.f, 0.f, 0.f};
    ec_acc[1] = (f32x4){0.f, 0.f, 0.f, 0.f};
    float cc_acc = 0.f;
    float ee_acc = 0.f;

    // one-time zeroing: ET rows 24..31, XT pad cols 168..191
    for (int i = tid; i < 8 * ST_STRIDE; i += 256)
        ET[(24 + i / ST_STRIDE) * ST_STRIDE + (i % ST_STRIDE)] = (bf16)0.0f;
    {
        bf16x4 z = {(bf16)0.f, (bf16)0.f, (bf16)0.f, (bf16)0.f};
        for (int i = tid; i < 64 * 6; i += 256) {
            int r = i / 6, p = i % 6;
            *reinterpret_cast<bf16x4*>(&XT[r * XT_STRIDE + IN_DIM + p * 4]) = z;
        }
    }

    for (int t = rblk; t < NT; t += RBLKS) {
        const int row0 = t * M_TILE;
        __syncthreads();   // previous iter's LDS readers done

        // ---- BATCH-ISSUE staging loads ----
        f32x4 xr[11], er[2];
#pragma unroll
        for (int j = 0; j < 11; ++j) {
            int idx = tid + j * 256;
            int r = idx / 42, c4 = idx - r * 42;
            int gr = row0 + r;
            f32x4 v = {0.f, 0.f, 0.f, 0.f};
            if (idx < 2688 && gr < N_ROWS)
                v = *reinterpret_cast<const f32x4*>(X + (size_t)gr * IN_DIM + c4 * 4);
            xr[j] = v;
        }
#pragma unroll
        for (int j = 0; j < 2; ++j) {
            int idx = tid + j * 256;
            int r = idx / 6, p = idx - r * 6;
            int gr = row0 + r;
            f32x4 v = {0.f, 0.f, 0.f, 0.f};
            if (idx < 384 && gr < N_ROWS)
                v = *reinterpret_cast<const f32x4*>(E + (size_t)gr * ERR_DIM + p * 4);
            er[j] = v;
        }

        // ---- consume in issue order: convert + LDS write ----
#pragma unroll
        for (int j = 0; j < 11; ++j) {
            int idx = tid + j * 256;
            if (idx < 2688) {
                int r = idx / 42, c4 = idx - r * 42;
                f32x4 v = xr[j];
                bf16x4 pk = {(bf16)v.x, (bf16)v.y, (bf16)v.z, (bf16)v.w};
                *reinterpret_cast<bf16x4*>(&XT[r * XT_STRIDE + c4 * 4]) = pk;
            }
        }
#pragma unroll
        for (int j = 0; j < 2; ++j) {
            int idx = tid + j * 256;
            if (idx < 384) {
                int r = idx / 6, p = idx - r * 6;
                f32x4 v = er[j];
                if (cg == 0)   // ee counted once, not 4x
                    ee_acc += v.x * v.x + v.y * v.y + v.z * v.z + v.w * v.w;
                int d0 = p * 4;
                ET[(d0 + 0) * ST_STRIDE + r] = (bf16)v.x;
                ET[(d0 + 1) * ST_STRIDE + r] = (bf16)v.y;
                ET[(d0 + 2) * ST_STRIDE + r] = (bf16)v.z;
                ET[(d0 + 3) * ST_STRIDE + r] = (bf16)v.w;
            }
        }
        __syncthreads();

        // --- phase A: S(64 rows x 16 cands per wave) = X @ W ---
        f32x4 acc[4];
#pragma unroll
        for (int mf = 0; mf < 4; ++mf) acc[mf] = (f32x4){0.f, 0.f, 0.f, 0.f};
#pragma unroll
        for (int kt = 0; kt < 6; ++kt) {
            bf16x8 a[4];
#pragma unroll
            for (int mf = 0; mf < 4; ++mf)
                a[mf] = *reinterpret_cast<const bf16x8*>(&XT[(mf * 16 + lo) * XT_STRIDE + kt * 32 + hi * 8]);
#pragma unroll
            for (int mf = 0; mf < 4; ++mf)
                acc[mf] = mfma16(a[mf], wf[kt], acc[mf]);
        }

        // --- bias + fast sigmoid + tail mask; cc accumulate; write SigT (wave-private) ---
#pragma unroll
        for (int mf = 0; mf < 4; ++mf) {
            const int rb = row0 + mf * 16 + hi * 4;
            f32x4 v = acc[mf];
            float s0 = fast_sigmoid(v.x + bv);
            float s1 = fast_sigmoid(v.y + bv);
            float s2 = fast_sigmoid(v.z + bv);
            float s3 = fast_sigmoid(v.w + bv);
            if (rb + 0 >= N_ROWS) s0 = 0.0f;
            if (rb + 1 >= N_ROWS) s1 = 0.0f;
            if (rb + 2 >= N_ROWS) s2 = 0.0f;
            if (rb + 3 >= N_ROWS) s3 = 0.0f;
            cc_acc += s0 * s0 + s1 * s1 + s2 * s2 + s3 * s3;
            bf16x4 pk = {(bf16)s0, (bf16)s1, (bf16)s2, (bf16)s3};
            *reinterpret_cast<bf16x4*>(&SigT[(wave * 16 + lo) * ST_STRIDE + mf * 16 + hi * 4]) = pk;
        }

        // --- phase B: ec += E^T @ S (wave-private SigT; same-wave lgkmcnt ordering) ---
#pragma unroll
        for (int kt2 = 0; kt2 < 2; ++kt2) {
            bf16x8 ea0 = *reinterpret_cast<const bf16x8*>(&ET[(0 * 16 + lo) * ST_STRIDE + kt2 * 32 + hi * 8]);
            bf16x8 ea1 = *reinterpret_cast<const bf16x8*>(&ET[(1 * 16 + lo) * ST_STRIDE + kt2 * 32 + hi * 8]);
            bf16x8 sb  = *reinterpret_cast<const bf16x8*>(&SigT[(wave * 16 + lo) * ST_STRIDE + kt2 * 32 + hi * 8]);
            ec_acc[0] = mfma16(ea0, sb, ec_acc[0]);
            ec_acc[1] = mfma16(ea1, sb, ec_acc[1]);
        }
    }

    // --- epilogue: flush partials into 8 spread copies ---
    const int copy = rblk & (NCOPY - 1);
#pragma unroll
    for (int rf = 0; rf < 2; ++rf)
#pragma unroll
        for (int rr = 0; rr < 4; ++rr) {
            int d = rf * 16 + hi * 4 + rr;
            if (d < ERR_DIM)
                atomicAdd(&ec_ws[copy * (ERR_DIM * CAND) + d * CAND + cand], ec_acc[rf][rr]);
        }
    {
        float v = cc_acc;
        v += __shfl_down(v, 32);
        v += __shfl_down(v, 16);
        if (lane < 16) atomicAdd(&cc_ws[copy * CAND + ct * 16 + lane], v);
    }
    if (cg == 0) {
#pragma unroll
        for (int off = 32; off > 0; off >>= 1) ee_acc += __shfl_down(ee_acc, off);
        if (lane == 0) red[wave] = ee_acc;
    }
    __syncthreads();
    if (cg == 0 && tid == 0) ee_ws[rblk] = red[0] + red[1] + red[2] + red[3];
}

__global__ __launch_bounds__(256) void finalize(const float* __restrict__ ec_ws,
                                                const float* __restrict__ cc_ws,
                                                const float* __restrict__ ee_ws,
                                                const float* __restrict__ r,
                                                float* __restrict__ out) {
    __shared__ float tmp[4];
    __shared__ float s_ee;
    int c = threadIdx.x;   // 0..255 = candidate
    float p = ee_ws[c];
#pragma unroll
    for (int off = 32; off > 0; off >>= 1) p += __shfl_down(p, off);
    if ((c & 63) == 0) tmp[c >> 6] = p;
    __syncthreads();
    if (c == 0) s_ee = tmp[0] + tmp[1] + tmp[2] + tmp[3];
    __syncthreads();
    float ee = s_ee;
    float ccv = 0.f;
#pragma unroll
    for (int cp = 0; cp < NCOPY; ++cp) ccv += cc_ws[cp * CAND + c];
    float left = 0.f;
#pragma unroll
    for (int d = 0; d < ERR_DIM; ++d) {
        float v = 0.f;
#pragma unroll
        for (int cp = 0; cp < NCOPY; ++cp) v += ec_ws[cp * (ERR_DIM * CAND) + d * CAND + c];
        left += v * v;
    }
    left /= ccv;
#pragma unroll
    for (int i = 0; i < 4; ++i) out[c * 4 + i] = left - (1.0f - r[i]) * ee;
}

extern "C" void kernel_launch(void* const* d_in, const int* in_sizes, int n_in,
                              void* d_out, int out_size, void* d_ws, size_t ws_size,
                              hipStream_t stream) {
    const float* X = (const float*)d_in[0];
    const float* E = (const float*)d_in[1];
    const float* W = (const float*)d_in[2];
    const float* B = (const float*)d_in[3];
    const float* r = (const float*)d_in[4];

    float* wsf   = (float*)d_ws;
    float* ec_ws = wsf + EC_F;
    float* cc_ws = wsf + CC_F;
    float* ee_ws = wsf + EE_F;
    bf16*  wp    = (bf16*)(wsf + WP_F);

    prep_kernel<<<24, 256, 0, stream>>>(W, wp, wsf);
    fused_main<<<4 * RBLKS, 256, 0, stream>>>(X, E, B, wp, ec_ws, cc_ws, ee_ws);
    finalize<<<1, 256, 0, stream>>>(ec_ws, cc_ws, ee_ws, r, (float*)d_out);
}